// Round 2
// baseline (226.729 us; speedup 1.0000x reference)
//
#include <hip/hip_runtime.h>

#define N_ENT   50000
#define N_ENT_P 50176
#define NDIM    256
#define BATCH   1024
#define MROWS   2048
#define BM      128
#define BN      256
#define NTILES  196
#define NSTRIP  16
#define SHIFT   30.0f

typedef __attribute__((ext_vector_type(8))) short short8;
typedef __attribute__((ext_vector_type(4))) float f32x4;

__device__ __forceinline__ unsigned short f2bf(float f) {
  unsigned int u = __float_as_uint(f);
  u += 0x7fffu + ((u >> 16) & 1u);          // RNE
  return (unsigned short)(u >> 16);
}

__device__ __forceinline__ void async16(const void* g, void* lds) {
  __builtin_amdgcn_global_load_lds(
      (const __attribute__((address_space(1))) unsigned int*)g,
      (__attribute__((address_space(3))) unsigned int*)lds,
      16, 0, 0);
}

// ---- K0: ent_w f32 -> bf16 bits, zero-pad rows [50000,50176) ----
__global__ void k_convert(const float* __restrict__ ent_w,
                          unsigned short* __restrict__ Wb) {
  int t = blockIdx.x * 256 + threadIdx.x;     // [0, 50176*64)
  int row = t >> 6, c4 = (t & 63) << 2;
  ushort4 v;
  if (row < N_ENT) {
    float4 f = *(const float4*)(ent_w + row * NDIM + c4);
    v.x = f2bf(f.x); v.y = f2bf(f.y); v.z = f2bf(f.z); v.w = f2bf(f.w);
  } else {
    v.x = v.y = v.z = v.w = 0;
  }
  *(ushort4*)(Wb + row * NDIM + c4) = v;
}

// ---- K1: BN stats (sum, sumsq); 16 rows/block, indices prefetched ----
__global__ void k_stats(const int* __restrict__ facts,
                        const float* __restrict__ ent_w,
                        const float* __restrict__ rel_w,
                        float* __restrict__ stats) {
  int seg = blockIdx.y;                        // 0=h, 1=t, 2=r
  int d = threadIdx.x;
  const float* tab = (seg == 2) ? rel_w : ent_w;
  int r0 = blockIdx.x * 16;
  int idxs[16];
#pragma unroll
  for (int i = 0; i < 16; ++i) idxs[i] = facts[(r0 + i) * 3 + seg];
  float s = 0.f, s2 = 0.f;
#pragma unroll
  for (int i = 0; i < 16; ++i) {
    float v = tab[idxs[i] * NDIM + d];
    s += v; s2 += v * v;
  }
  atomicAdd(&stats[(seg * 2 + 0) * NDIM + d], s);
  atomicAdd(&stats[(seg * 2 + 1) * NDIM + d], s2);
}

// ---- K2: BN apply + alpha bilinear -> head/tail vec (bf16) + exact label dots ----
__global__ void k_vectors(const int* __restrict__ facts, const int* __restrict__ arch,
                          const float* __restrict__ ent_w, const float* __restrict__ rel_w,
                          const float* __restrict__ bne_g, const float* __restrict__ bne_b,
                          const float* __restrict__ bnr_g, const float* __restrict__ bnr_b,
                          const float* __restrict__ stats,
                          unsigned short* __restrict__ HVb, float* __restrict__ zlab) {
  __shared__ float sh_he[256], sh_te[256], sh_re[256], sh_alpha[64], sh_red[16];
  int b = blockIdx.x, d = threadIdx.x;
  int h = facts[b * 3 + 0], t = facts[b * 3 + 1], r = facts[b * 3 + 2];
  const float inv = 1.0f / (float)BATCH;
  float mh = stats[0 * 256 + d] * inv, vh = stats[1 * 256 + d] * inv - mh * mh;
  float mt = stats[2 * 256 + d] * inv, vt = stats[3 * 256 + d] * inv - mt * mt;
  float mr = stats[4 * 256 + d] * inv, vr = stats[5 * 256 + d] * inv - mr * mr;
  float sch = rsqrtf(vh + 1e-5f) * bne_g[d], shh = bne_b[d] - mh * sch;
  float sct = rsqrtf(vt + 1e-5f) * bne_g[d], sht = bne_b[d] - mt * sct;
  float scr = rsqrtf(vr + 1e-5f) * bnr_g[d], shr = bnr_b[d] - mr * scr;
  sh_he[d] = ent_w[h * NDIM + d] * sch + shh;
  sh_te[d] = ent_w[t * NDIM + d] * sct + sht;
  sh_re[d] = rel_w[r * NDIM + d] * scr + shr;
  if (d < 64) {
    int a = arch[d];
    sh_alpha[d] = (a == 0) ? 0.f : ((a == 1) ? 1.f : -1.f);
  }
  __syncthreads();
  int k = d >> 6, l = d & 63;
  float hv = 0.f, tv = 0.f;
#pragma unroll
  for (int i = 0; i < 4; ++i) {
    float re_i = sh_re[i * 64 + l];
#pragma unroll
    for (int j = 0; j < 4; ++j) {
      hv += sh_alpha[i * 16 + j * 4 + k] * re_i * sh_te[j * 64 + l];
      tv += sh_alpha[i * 16 + k * 4 + j] * re_i * sh_he[j * 64 + l];
    }
  }
  HVb[b * NDIM + d] = f2bf(hv);
  HVb[(BATCH + b) * NDIM + d] = f2bf(tv);
  float ph = hv * ent_w[h * NDIM + d];
  float pt = tv * ent_w[t * NDIM + d];
  for (int m = 1; m < 64; m <<= 1) { ph += __shfl_xor(ph, m); pt += __shfl_xor(pt, m); }
  int wid = d >> 6;
  if ((d & 63) == 0) { sh_red[wid] = ph; sh_red[8 + wid] = pt; }
  __syncthreads();
  if (d == 0) {
    zlab[b] = sh_red[0] + sh_red[1] + sh_red[2] + sh_red[3];
    zlab[BATCH + b] = sh_red[8] + sh_red[9] + sh_red[10] + sh_red[11];
  }
}

// ---- K3: bf16 MFMA GEMM (2048 x 50176 x 256).
//   A: per-wave 64 rows x 256 K held ENTIRELY in registers (128 VGPR),
//   loaded once from global (L2-resident). LDS holds only the B ring
//   (4 x 16 KB, depth-3 prefetch, counted vmcnt(4) — never 0 in loop).
//   Per job: 4 ds_read_b128 (B) : 16 MFMA -> matrix pipe is the floor.
//   setprio(1) around the MFMA cluster (T5). Per-tile exp/power-sum
//   flush via shfl + atomics (frees the 32 power-sum VGPRs). ----
__global__ void __launch_bounds__(512, 2)
k_gemm(const unsigned short* __restrict__ HVb, const unsigned short* __restrict__ Wb,
       float* __restrict__ m1, float* __restrict__ m2) {
  __shared__ __align__(16) unsigned short Bs[4 * BN * 32];   // 64 KB ring
  const int tid = threadIdx.x;
  const int lane = tid & 63, wid = tid >> 6;     // 8 waves (2M x 4N)
  const int L = blockIdx.x;                      // [0,256)
  const int xcd = L & 7, rr = L >> 3;            // rr in [0,32)
  const int strip = xcd * 2 + (rr >> 4);         // [0,16): strip pinned to one XCD
  const int bm = (rr & 15) * BM;
  const int wm = (wid >> 2) * 64, wn = (wid & 3) * 64;
  const int q = lane >> 4, ln = lane & 15;

  const int ntmine = NTILES / NSTRIP + (strip < (NTILES % NSTRIP) ? 1 : 0); // 12 or 13
  const int njobs = ntmine * 8;                  // 32-K jobs

  // ---- A fragments for this wave: 4 m-tiles x 8 k-chunks, straight from global ----
  short8 a[4][8];
#pragma unroll
  for (int mi = 0; mi < 4; ++mi)
#pragma unroll
    for (int c = 0; c < 8; ++c)
      a[mi][c] = *(const short8*)(HVb + (bm + wm + mi * 16 + ln) * NDIM + c * 32 + q * 8);

  // B LDS read byte-offsets (swizzled), thread-invariant per ni
  int boff[4];
#pragma unroll
  for (int ni = 0; ni < 4; ++ni) {
    int row = wn + ni * 16 + ln;
    boff[ni] = row * 64 + ((q ^ ((row >> 1) & 3)) << 4);
  }

  // ---- B tile stage: 2 async16/thread; dummy tail re-stage keeps vmcnt exact ----
  auto stageB = [&](int j2, int buf) {
    int jj = (j2 < njobs) ? j2 : 0;
    int nt = strip + (jj >> 3) * NSTRIP;
    int kc = (jj & 7) * 32;
    const unsigned short* gbase = Wb + nt * (BN * NDIM) + kc;
#pragma unroll
    for (int i = 0; i < 2; ++i) {
      int G = (wid * 2 + i) * 64 + lane;         // [0,1024)
      int row = G >> 2, slot = G & 3;            // 256 rows x 4 granules
      int kg = slot ^ ((row >> 1) & 3);
      async16(gbase + row * NDIM + kg * 8,
              (char*)Bs + buf * 16384 + (wid * 2 + i) * 1024);
    }
  };
  stageB(0, 0); stageB(1, 1); stageB(2, 2);      // prologue: depth-3 prefetch

  int j = 0;
  for (int ti = 0; ti < ntmine; ++ti) {
    f32x4 acc[4][4] = {};
#pragma unroll
    for (int c = 0; c < 8; ++c) {
      // all but the newest 4 vmem ops retired -> B(j) (and A regs) landed
      asm volatile("s_waitcnt vmcnt(4)" ::: "memory");
      __builtin_amdgcn_s_barrier();
      asm volatile("" ::: "memory");             // no stage hoisting above barrier
      stageB(j + 3, (c + 3) & 3);                // overlaps this job's compute
      const char* Bc = (const char*)Bs + (c & 3) * 16384;
      short8 bb[4];
#pragma unroll
      for (int ni = 0; ni < 4; ++ni)
        bb[ni] = *(const short8*)(Bc + boff[ni]);
      __builtin_amdgcn_s_setprio(1);
#pragma unroll
      for (int mi = 0; mi < 4; ++mi)
#pragma unroll
        for (int ni = 0; ni < 4; ++ni)
          acc[mi][ni] = __builtin_amdgcn_mfma_f32_16x16x32_bf16(a[mi][c], bb[ni], acc[mi][ni], 0, 0, 0);
      __builtin_amdgcn_s_setprio(0);
      ++j;
    }
    // per-tile consume: exp power sums, 16-lane reduce, atomic flush
    // (pad cols contribute e^-30 ~ 0)
#pragma unroll
    for (int mi = 0; mi < 4; ++mi)
#pragma unroll
      for (int reg = 0; reg < 4; ++reg) {
        float s1 = 0.f, s2 = 0.f;
#pragma unroll
        for (int ni = 0; ni < 4; ++ni) {
          float e1 = __expf(acc[mi][ni][reg] - SHIFT);
          s1 += e1; s2 += e1 * e1;
        }
        for (int m = 1; m < 16; m <<= 1) { s1 += __shfl_xor(s1, m); s2 += __shfl_xor(s2, m); }
        if (ln == 0) {
          int grow = bm + wm + mi * 16 + q * 4 + reg;
          atomicAdd(&m1[grow], s1);
          atomicAdd(&m2[grow], s2);
        }
      }
  }
  // drain in-flight dummy LDS-DMA before this block's LDS can be reassigned
  asm volatile("s_waitcnt vmcnt(0)" ::: "memory");
}

// ---- K4: per-row loss assembly + scalar reduce ----
__global__ void k_finalize(const float* __restrict__ m1, const float* __restrict__ m2,
                           const float* __restrict__ zlab, float* __restrict__ out) {
  __shared__ float red[16];
  int tid = threadIdx.x;  // 1024 threads
  float local = 0.f;
  for (int r = tid; r < MROWS; r += 1024) {
    float M1 = m1[r];
    float lse = SHIFT + logf(M1);
    float zl = zlab[r];
    float lp = fmaxf(zl - lse, -100.f);                 // log p_label
    float pl = __expf(zl - lse);
    float l1m = fmaxf(log1pf(-pl), -100.f);             // log(1-p_label)
    float iM1 = 1.f / M1;
    float r2 = m2[r] * iM1 * iM1;
    // sum_e log1p(-p_e) = -(1 + sum p^2/2 + O(p^3)); sum p == 1 exactly
    float series = -(1.f + 0.5f * r2);
    local += lp - l1m + series;
  }
  for (int m = 1; m < 64; m <<= 1) local += __shfl_xor(local, m);
  if ((tid & 63) == 0) red[tid >> 6] = local;
  __syncthreads();
  if (tid == 0) {
    float s = 0.f;
    for (int i = 0; i < 16; ++i) s += red[i];
    out[0] = -s / ((float)BATCH * (float)N_ENT);
  }
}

extern "C" void kernel_launch(void* const* d_in, const int* in_sizes, int n_in,
                              void* d_out, int out_size, void* d_ws, size_t ws_size,
                              hipStream_t stream) {
  const int* facts = (const int*)d_in[0];
  const int* arch = (const int*)d_in[1];
  const float* ent_w = (const float*)d_in[2];
  const float* rel_w = (const float*)d_in[3];
  const float* bne_g = (const float*)d_in[4];
  const float* bne_b = (const float*)d_in[5];
  const float* bnr_g = (const float*)d_in[6];
  const float* bnr_b = (const float*)d_in[7];
  char* ws = (char*)d_ws;
  // layout: [stats 6144][m1 8192][m2 8192][zlab 8192][HVb 1MB][Wb 25.7MB]
  float* stats = (float*)ws;
  float* m1 = (float*)(ws + 6144);
  float* m2 = (float*)(ws + 14336);
  float* zlab = (float*)(ws + 22528);
  unsigned short* HVb = (unsigned short*)(ws + 30720);
  unsigned short* Wb = (unsigned short*)(ws + 30720 + 1048576);

  hipMemsetAsync(ws, 0, 22528, stream);  // stats + m1 + m2
  k_convert<<<dim3((N_ENT_P * 64) / 256), dim3(256), 0, stream>>>(ent_w, Wb);
  k_stats<<<dim3(64, 3), dim3(256), 0, stream>>>(facts, ent_w, rel_w, stats);
  k_vectors<<<dim3(BATCH), dim3(256), 0, stream>>>(facts, arch, ent_w, rel_w,
                                                   bne_g, bne_b, bnr_g, bnr_b,
                                                   stats, HVb, zlab);
  k_gemm<<<dim3(256), dim3(512), 0, stream>>>(HVb, Wb, m1, m2);
  k_finalize<<<dim3(1), dim3(1024), 0, stream>>>(m1, m2, zlab, (float*)d_out);
}

// Round 3
// 175.661 us; speedup vs baseline: 1.2907x; 1.2907x over previous
//
#include <hip/hip_runtime.h>

#define N_ENT   50000
#define N_ENT_P 50176
#define NDIM    256
#define BATCH   1024
#define MROWS   2048
#define BM      128
#define BN      256
#define NTILES  196
#define NSTRIP  16
#define SHIFT   30.0f

typedef __attribute__((ext_vector_type(8))) short short8;
typedef __attribute__((ext_vector_type(4))) float f32x4;

__device__ __forceinline__ unsigned short f2bf(float f) {
  unsigned int u = __float_as_uint(f);
  u += 0x7fffu + ((u >> 16) & 1u);          // RNE
  return (unsigned short)(u >> 16);
}

__device__ __forceinline__ void async16(const void* g, void* lds) {
  __builtin_amdgcn_global_load_lds(
      (const __attribute__((address_space(1))) unsigned int*)g,
      (__attribute__((address_space(3))) unsigned int*)lds,
      16, 0, 0);
}

// ---- K0: ent_w f32 -> bf16 bits, zero-pad rows [50000,50176) ----
__global__ void k_convert(const float* __restrict__ ent_w,
                          unsigned short* __restrict__ Wb) {
  int t = blockIdx.x * 256 + threadIdx.x;     // [0, 50176*64)
  int row = t >> 6, c4 = (t & 63) << 2;
  ushort4 v;
  if (row < N_ENT) {
    float4 f = *(const float4*)(ent_w + row * NDIM + c4);
    v.x = f2bf(f.x); v.y = f2bf(f.y); v.z = f2bf(f.z); v.w = f2bf(f.w);
  } else {
    v.x = v.y = v.z = v.w = 0;
  }
  *(ushort4*)(Wb + row * NDIM + c4) = v;
}

// ---- K1: BN stats (sum, sumsq); 16 rows/block, indices prefetched ----
__global__ void k_stats(const int* __restrict__ facts,
                        const float* __restrict__ ent_w,
                        const float* __restrict__ rel_w,
                        float* __restrict__ stats) {
  int seg = blockIdx.y;                        // 0=h, 1=t, 2=r
  int d = threadIdx.x;
  const float* tab = (seg == 2) ? rel_w : ent_w;
  int r0 = blockIdx.x * 16;
  int idxs[16];
#pragma unroll
  for (int i = 0; i < 16; ++i) idxs[i] = facts[(r0 + i) * 3 + seg];
  float s = 0.f, s2 = 0.f;
#pragma unroll
  for (int i = 0; i < 16; ++i) {
    float v = tab[idxs[i] * NDIM + d];
    s += v; s2 += v * v;
  }
  atomicAdd(&stats[(seg * 2 + 0) * NDIM + d], s);
  atomicAdd(&stats[(seg * 2 + 1) * NDIM + d], s2);
}

// ---- K2: BN apply + alpha bilinear -> head/tail vec (bf16) + exact label dots ----
__global__ void k_vectors(const int* __restrict__ facts, const int* __restrict__ arch,
                          const float* __restrict__ ent_w, const float* __restrict__ rel_w,
                          const float* __restrict__ bne_g, const float* __restrict__ bne_b,
                          const float* __restrict__ bnr_g, const float* __restrict__ bnr_b,
                          const float* __restrict__ stats,
                          unsigned short* __restrict__ HVb, float* __restrict__ zlab) {
  __shared__ float sh_he[256], sh_te[256], sh_re[256], sh_alpha[64], sh_red[16];
  int b = blockIdx.x, d = threadIdx.x;
  int h = facts[b * 3 + 0], t = facts[b * 3 + 1], r = facts[b * 3 + 2];
  const float inv = 1.0f / (float)BATCH;
  float mh = stats[0 * 256 + d] * inv, vh = stats[1 * 256 + d] * inv - mh * mh;
  float mt = stats[2 * 256 + d] * inv, vt = stats[3 * 256 + d] * inv - mt * mt;
  float mr = stats[4 * 256 + d] * inv, vr = stats[5 * 256 + d] * inv - mr * mr;
  float sch = rsqrtf(vh + 1e-5f) * bne_g[d], shh = bne_b[d] - mh * sch;
  float sct = rsqrtf(vt + 1e-5f) * bne_g[d], sht = bne_b[d] - mt * sct;
  float scr = rsqrtf(vr + 1e-5f) * bnr_g[d], shr = bnr_b[d] - mr * scr;
  sh_he[d] = ent_w[h * NDIM + d] * sch + shh;
  sh_te[d] = ent_w[t * NDIM + d] * sct + sht;
  sh_re[d] = rel_w[r * NDIM + d] * scr + shr;
  if (d < 64) {
    int a = arch[d];
    sh_alpha[d] = (a == 0) ? 0.f : ((a == 1) ? 1.f : -1.f);
  }
  __syncthreads();
  int k = d >> 6, l = d & 63;
  float hv = 0.f, tv = 0.f;
#pragma unroll
  for (int i = 0; i < 4; ++i) {
    float re_i = sh_re[i * 64 + l];
#pragma unroll
    for (int j = 0; j < 4; ++j) {
      hv += sh_alpha[i * 16 + j * 4 + k] * re_i * sh_te[j * 64 + l];
      tv += sh_alpha[i * 16 + k * 4 + j] * re_i * sh_he[j * 64 + l];
    }
  }
  HVb[b * NDIM + d] = f2bf(hv);
  HVb[(BATCH + b) * NDIM + d] = f2bf(tv);
  float ph = hv * ent_w[h * NDIM + d];
  float pt = tv * ent_w[t * NDIM + d];
  for (int m = 1; m < 64; m <<= 1) { ph += __shfl_xor(ph, m); pt += __shfl_xor(pt, m); }
  int wid = d >> 6;
  if ((d & 63) == 0) { sh_red[wid] = ph; sh_red[8 + wid] = pt; }
  __syncthreads();
  if (d == 0) {
    zlab[b] = sh_red[0] + sh_red[1] + sh_red[2] + sh_red[3];
    zlab[BATCH + b] = sh_red[8] + sh_red[9] + sh_red[10] + sh_red[11];
  }
}

// ---- K3: bf16 MFMA GEMM (2048 x 50176 x 256).
//   A strip resident in LDS (64 KB, staged once); B ring (4 x 16 KB, depth-3,
//   counted vmcnt(4)). CROSS-JOB fragment software pipeline: at job j, issue
//   ds_reads of job j+1's fragments (double-buffered regs), then MFMA job j —
//   LDS pipe and matrix pipe overlap instead of alternating. A free
//   lgkmcnt(0) at phase end makes the buf-(j)&3 overwrite by stage(j+4) safe.
//   Register ps power-sums, one atomic round per block (no per-tile atomics).
__global__ void __launch_bounds__(512, 2)
k_gemm(const unsigned short* __restrict__ HVb, const unsigned short* __restrict__ Wb,
       float* __restrict__ m1, float* __restrict__ m2) {
  __shared__ __align__(16) unsigned short As[4 * BM * 64];   // 64 KB, 4 chunks (64-K)
  __shared__ __align__(16) unsigned short Bs[4 * BN * 32];   // 64 KB ring (32-K bufs)
  const int tid = threadIdx.x;
  const int lane = tid & 63, wid = tid >> 6;     // 8 waves (2M x 4N)
  const int L = blockIdx.x;                      // [0,256)
  const int xcd = L & 7, rr = L >> 3;            // rr in [0,32)
  const int strip = xcd * 2 + (rr >> 4);         // [0,16): strip pinned to one XCD
  const int bm = (rr & 15) * BM;
  const int wm = (wid >> 2) * 64, wn = (wid & 3) * 64;
  const int q = lane >> 4, ln = lane & 15;

  const int ntmine = NTILES / NSTRIP + (strip < (NTILES % NSTRIP) ? 1 : 0); // 12 or 13
  const int njobs = ntmine * 8;                  // 32-K jobs

  // ---- stage A strip once: 4 chunks x 1024 granules ----
#pragma unroll
  for (int c = 0; c < 4; ++c)
#pragma unroll
    for (int i = 0; i < 2; ++i) {
      int G = (wid * 2 + i) * 64 + lane;         // [0,1024)
      int row = G >> 3, slot = G & 7;
      int kg = slot ^ (row & 7);
      async16(HVb + (bm + row) * NDIM + c * 64 + kg * 8,
              (char*)As + c * 16384 + (wid * 2 + i) * 1024);
    }

  // frag read offsets (swizzled), per-thread invariants
  int aoffq[4], boff[4];
#pragma unroll
  for (int mi = 0; mi < 4; ++mi) {
    int row = wm + mi * 16 + ln;
    aoffq[mi] = row * 128 + ((q ^ (row & 7)) << 4);   // chunk-parity toggles bit6
  }
#pragma unroll
  for (int ni = 0; ni < 4; ++ni) {
    int row = wn + ni * 16 + ln;
    boff[ni] = row * 64 + ((q ^ ((row >> 1) & 3)) << 4);
  }

  // B stage source offsets, per-thread invariants
  int ssoff[2], sdoff[2];
#pragma unroll
  for (int i = 0; i < 2; ++i) {
    int G = (wid * 2 + i) * 64 + lane;           // [0,1024)
    int row = G >> 2, slot = G & 3;              // 256 rows x 4 granules
    int kg = slot ^ ((row >> 1) & 3);
    ssoff[i] = row * NDIM + kg * 8;
    sdoff[i] = (wid * 2 + i) * 1024;
  }
  auto stageB = [&](int j2, int buf) {
    int jj = (j2 < njobs) ? j2 : 0;              // dummy tail keeps vmcnt exact
    int nt = strip + (jj >> 3) * NSTRIP;
    const unsigned short* gbase = Wb + nt * (BN * NDIM) + (jj & 7) * 32;
#pragma unroll
    for (int i = 0; i < 2; ++i)
      async16(gbase + ssoff[i], (char*)Bs + buf * 16384 + sdoff[i]);
  };
  stageB(0, 0); stageB(1, 1); stageB(2, 2);      // depth-3 prefetch

  // double-buffered fragment registers (named -> never scratch)
  short8 fa0[4], fb0[4], fa1[4], fb1[4];
  float ps1[4][4] = {}, ps2[4][4] = {};

#define RD(CN, FA, FB)                                                        \
  {                                                                           \
    const char* Ac = (const char*)As + ((((CN)) & 7) >> 1) * 16384;           \
    const char* Bc = (const char*)Bs + (((CN)) & 3) * 16384;                  \
    const int axor = (((CN)) & 1) << 6;                                       \
    _Pragma("unroll") for (int mi = 0; mi < 4; ++mi)                          \
        FA[mi] = *(const short8*)(Ac + (aoffq[mi] ^ axor));                   \
    _Pragma("unroll") for (int ni = 0; ni < 4; ++ni)                          \
        FB[ni] = *(const short8*)(Bc + boff[ni]);                             \
  }
#define MM(FA, FB)                                                            \
  {                                                                           \
    __builtin_amdgcn_s_setprio(1);                                            \
    _Pragma("unroll") for (int mi = 0; mi < 4; ++mi)                          \
        _Pragma("unroll") for (int ni = 0; ni < 4; ++ni)                      \
            acc[mi][ni] = __builtin_amdgcn_mfma_f32_16x16x32_bf16(            \
                FA[mi], FB[ni], acc[mi][ni], 0, 0, 0);                        \
    __builtin_amdgcn_s_setprio(0);                                            \
  }
#define PH(C, FAR, FBR, FAU, FBU)                                             \
  asm volatile("s_waitcnt vmcnt(4)" ::: "memory");                            \
  __builtin_amdgcn_s_barrier();                                               \
  RD((C) + 1, FAR, FBR);                                                      \
  stageB(ti * 8 + (C) + 4, ((C) + 4) & 3);                                    \
  __builtin_amdgcn_sched_barrier(0);                                          \
  MM(FAU, FBU);                                                               \
  asm volatile("s_waitcnt lgkmcnt(0)" ::: "memory");

  // prologue: frags(0) into set0; stage(3)
  asm volatile("s_waitcnt vmcnt(4)" ::: "memory");   // A + stage(0) retired
  __builtin_amdgcn_s_barrier();
  RD(0, fa0, fb0);
  stageB(3, 3);
  asm volatile("s_waitcnt lgkmcnt(0)" ::: "memory"); // reads(0) retired pre-loop

  for (int ti = 0; ti < ntmine; ++ti) {
    f32x4 acc[4][4] = {};
    PH(0, fa1, fb1, fa0, fb0)
    PH(1, fa0, fb0, fa1, fb1)
    PH(2, fa1, fb1, fa0, fb0)
    PH(3, fa0, fb0, fa1, fb1)
    PH(4, fa1, fb1, fa0, fb0)
    PH(5, fa0, fb0, fa1, fb1)
    PH(6, fa1, fb1, fa0, fb0)
    PH(7, fa0, fb0, fa1, fb1)
    // consume acc into register power sums (pad cols contribute e^-30 ~ 0)
#pragma unroll
    for (int mi = 0; mi < 4; ++mi)
#pragma unroll
      for (int reg = 0; reg < 4; ++reg) {
        float s1 = 0.f, s2 = 0.f;
#pragma unroll
        for (int ni = 0; ni < 4; ++ni) {
          float e1 = __expf(acc[mi][ni][reg] - SHIFT);
          s1 += e1; s2 += e1 * e1;
        }
        ps1[mi][reg] += s1;
        ps2[mi][reg] += s2;
      }
  }
#undef PH
#undef MM
#undef RD
  // drain in-flight dummy LDS-DMA before LDS reuse / kernel end
  asm volatile("s_waitcnt vmcnt(0)" ::: "memory");

  // one reduce + atomic round per block
#pragma unroll
  for (int mi = 0; mi < 4; ++mi)
#pragma unroll
    for (int reg = 0; reg < 4; ++reg) {
      float s1 = ps1[mi][reg], s2 = ps2[mi][reg];
      for (int m = 1; m < 16; m <<= 1) { s1 += __shfl_xor(s1, m); s2 += __shfl_xor(s2, m); }
      if (ln == 0) {
        int grow = bm + wm + mi * 16 + q * 4 + reg;
        atomicAdd(&m1[grow], s1);
        atomicAdd(&m2[grow], s2);
      }
    }
}

// ---- K4: per-row loss assembly + scalar reduce ----
__global__ void k_finalize(const float* __restrict__ m1, const float* __restrict__ m2,
                           const float* __restrict__ zlab, float* __restrict__ out) {
  __shared__ float red[16];
  int tid = threadIdx.x;  // 1024 threads
  float local = 0.f;
  for (int r = tid; r < MROWS; r += 1024) {
    float M1 = m1[r];
    float lse = SHIFT + logf(M1);
    float zl = zlab[r];
    float lp = fmaxf(zl - lse, -100.f);                 // log p_label
    float pl = __expf(zl - lse);
    float l1m = fmaxf(log1pf(-pl), -100.f);             // log(1-p_label)
    float iM1 = 1.f / M1;
    float r2 = m2[r] * iM1 * iM1;
    // sum_e log1p(-p_e) = -(1 + sum p^2/2 + O(p^3)); sum p == 1 exactly
    float series = -(1.f + 0.5f * r2);
    local += lp - l1m + series;
  }
  for (int m = 1; m < 64; m <<= 1) local += __shfl_xor(local, m);
  if ((tid & 63) == 0) red[tid >> 6] = local;
  __syncthreads();
  if (tid == 0) {
    float s = 0.f;
    for (int i = 0; i < 16; ++i) s += red[i];
    out[0] = -s / ((float)BATCH * (float)N_ENT);
  }
}

extern "C" void kernel_launch(void* const* d_in, const int* in_sizes, int n_in,
                              void* d_out, int out_size, void* d_ws, size_t ws_size,
                              hipStream_t stream) {
  const int* facts = (const int*)d_in[0];
  const int* arch = (const int*)d_in[1];
  const float* ent_w = (const float*)d_in[2];
  const float* rel_w = (const float*)d_in[3];
  const float* bne_g = (const float*)d_in[4];
  const float* bne_b = (const float*)d_in[5];
  const float* bnr_g = (const float*)d_in[6];
  const float* bnr_b = (const float*)d_in[7];
  char* ws = (char*)d_ws;
  // layout: [stats 6144][m1 8192][m2 8192][zlab 8192][HVb 1MB][Wb 25.7MB]
  float* stats = (float*)ws;
  float* m1 = (float*)(ws + 6144);
  float* m2 = (float*)(ws + 14336);
  float* zlab = (float*)(ws + 22528);
  unsigned short* HVb = (unsigned short*)(ws + 30720);
  unsigned short* Wb = (unsigned short*)(ws + 30720 + 1048576);

  hipMemsetAsync(ws, 0, 22528, stream);  // stats + m1 + m2
  k_convert<<<dim3((N_ENT_P * 64) / 256), dim3(256), 0, stream>>>(ent_w, Wb);
  k_stats<<<dim3(64, 3), dim3(256), 0, stream>>>(facts, ent_w, rel_w, stats);
  k_vectors<<<dim3(BATCH), dim3(256), 0, stream>>>(facts, arch, ent_w, rel_w,
                                                   bne_g, bne_b, bnr_g, bnr_b,
                                                   stats, HVb, zlab);
  k_gemm<<<dim3(256), dim3(512), 0, stream>>>(HVb, Wb, m1, m2);
  k_finalize<<<dim3(1), dim3(1024), 0, stream>>>(m1, m2, zlab, (float*)d_out);
}

// Round 4
// 172.721 us; speedup vs baseline: 1.3127x; 1.0170x over previous
//
#include <hip/hip_runtime.h>

#define N_ENT   50000
#define N_ENT_P 50176
#define NDIM    256
#define BATCH   1024
#define MROWS   2048
#define AM      64
#define BN      256
#define NTILES  196
#define NSTRIP  16
#define SHIFT   30.0f

typedef __attribute__((ext_vector_type(8))) short short8;
typedef __attribute__((ext_vector_type(4))) float f32x4;

__device__ __forceinline__ unsigned short f2bf(float f) {
  unsigned int u = __float_as_uint(f);
  u += 0x7fffu + ((u >> 16) & 1u);          // RNE
  return (unsigned short)(u >> 16);
}

__device__ __forceinline__ void async16(const void* g, void* lds) {
  __builtin_amdgcn_global_load_lds(
      (const __attribute__((address_space(1))) unsigned int*)g,
      (__attribute__((address_space(3))) unsigned int*)lds,
      16, 0, 0);
}

// ---- K0: ent_w f32 -> bf16 MFMA-FRAGMENT layout, zero-pad ntiles >= 3125.
//   Wb granule (ntile, kc, lane=q*16+ln) = B[ntile*16+ln][kc*32+q*8 .. +7]:
//   16 B contiguous per lane, 1024 B contiguous per wave-fragment. ----
__global__ void k_convert(const float* __restrict__ ent_w,
                          unsigned short* __restrict__ Wb) {
  int nt = blockIdx.x;                        // [0, 3136)
  int tid = threadIdx.x;                      // 256
#pragma unroll
  for (int h = 0; h < 2; ++h) {
    int g = h * 256 + tid;                    // granule in [0,512)
    int kc = g >> 6, lane = g & 63;
    int qq = lane >> 4, lnn = lane & 15;
    int row = nt * 16 + lnn, col = kc * 32 + qq * 8;
    short8 v;
    if (row < N_ENT) {
      const float* s = ent_w + row * NDIM + col;
      float4 f0 = *(const float4*)s, f1 = *(const float4*)(s + 4);
      v[0] = (short)f2bf(f0.x); v[1] = (short)f2bf(f0.y);
      v[2] = (short)f2bf(f0.z); v[3] = (short)f2bf(f0.w);
      v[4] = (short)f2bf(f1.x); v[5] = (short)f2bf(f1.y);
      v[6] = (short)f2bf(f1.z); v[7] = (short)f2bf(f1.w);
    } else {
      v = (short8)(0);
    }
    *(short8*)(Wb + nt * 4096 + g * 8) = v;
  }
}

// ---- K1: BN stats (sum, sumsq); 16 rows/block, indices prefetched ----
__global__ void k_stats(const int* __restrict__ facts,
                        const float* __restrict__ ent_w,
                        const float* __restrict__ rel_w,
                        float* __restrict__ stats) {
  int seg = blockIdx.y;                        // 0=h, 1=t, 2=r
  int d = threadIdx.x;
  const float* tab = (seg == 2) ? rel_w : ent_w;
  int r0 = blockIdx.x * 16;
  int idxs[16];
#pragma unroll
  for (int i = 0; i < 16; ++i) idxs[i] = facts[(r0 + i) * 3 + seg];
  float s = 0.f, s2 = 0.f;
#pragma unroll
  for (int i = 0; i < 16; ++i) {
    float v = tab[idxs[i] * NDIM + d];
    s += v; s2 += v * v;
  }
  atomicAdd(&stats[(seg * 2 + 0) * NDIM + d], s);
  atomicAdd(&stats[(seg * 2 + 1) * NDIM + d], s2);
}

// ---- K2: BN apply + alpha bilinear -> head/tail vec (bf16) + exact label dots ----
__global__ void k_vectors(const int* __restrict__ facts, const int* __restrict__ arch,
                          const float* __restrict__ ent_w, const float* __restrict__ rel_w,
                          const float* __restrict__ bne_g, const float* __restrict__ bne_b,
                          const float* __restrict__ bnr_g, const float* __restrict__ bnr_b,
                          const float* __restrict__ stats,
                          unsigned short* __restrict__ HVb, float* __restrict__ zlab) {
  __shared__ float sh_he[256], sh_te[256], sh_re[256], sh_alpha[64], sh_red[16];
  int b = blockIdx.x, d = threadIdx.x;
  int h = facts[b * 3 + 0], t = facts[b * 3 + 1], r = facts[b * 3 + 2];
  const float inv = 1.0f / (float)BATCH;
  float mh = stats[0 * 256 + d] * inv, vh = stats[1 * 256 + d] * inv - mh * mh;
  float mt = stats[2 * 256 + d] * inv, vt = stats[3 * 256 + d] * inv - mt * mt;
  float mr = stats[4 * 256 + d] * inv, vr = stats[5 * 256 + d] * inv - mr * mr;
  float sch = rsqrtf(vh + 1e-5f) * bne_g[d], shh = bne_b[d] - mh * sch;
  float sct = rsqrtf(vt + 1e-5f) * bne_g[d], sht = bne_b[d] - mt * sct;
  float scr = rsqrtf(vr + 1e-5f) * bnr_g[d], shr = bnr_b[d] - mr * scr;
  sh_he[d] = ent_w[h * NDIM + d] * sch + shh;
  sh_te[d] = ent_w[t * NDIM + d] * sct + sht;
  sh_re[d] = rel_w[r * NDIM + d] * scr + shr;
  if (d < 64) {
    int a = arch[d];
    sh_alpha[d] = (a == 0) ? 0.f : ((a == 1) ? 1.f : -1.f);
  }
  __syncthreads();
  int k = d >> 6, l = d & 63;
  float hv = 0.f, tv = 0.f;
#pragma unroll
  for (int i = 0; i < 4; ++i) {
    float re_i = sh_re[i * 64 + l];
#pragma unroll
    for (int j = 0; j < 4; ++j) {
      hv += sh_alpha[i * 16 + j * 4 + k] * re_i * sh_te[j * 64 + l];
      tv += sh_alpha[i * 16 + k * 4 + j] * re_i * sh_he[j * 64 + l];
    }
  }
  HVb[b * NDIM + d] = f2bf(hv);
  HVb[(BATCH + b) * NDIM + d] = f2bf(tv);
  float ph = hv * ent_w[h * NDIM + d];
  float pt = tv * ent_w[t * NDIM + d];
  for (int m = 1; m < 64; m <<= 1) { ph += __shfl_xor(ph, m); pt += __shfl_xor(pt, m); }
  int wid = d >> 6;
  if ((d & 63) == 0) { sh_red[wid] = ph; sh_red[8 + wid] = pt; }
  __syncthreads();
  if (d == 0) {
    zlab[b] = sh_red[0] + sh_red[1] + sh_red[2] + sh_red[3];
    zlab[BATCH + b] = sh_red[8] + sh_red[9] + sh_red[10] + sh_red[11];
  }
}

// ---- K3: bf16 MFMA GEMM (2048 x 50176 x 256).
//   A (64 rows x 256 K) staged once to LDS (32 KB, XOR-swizzled, zero-conflict);
//   B read DIRECTLY global->VGPR from the fragment-laid Wb (1024 B coalesced
//   per wave-frag), double-buffered, compiler-counted waits. NO barriers and
//   NO LDS traffic for B in the main loop: load work splits across the LDS
//   pipe (A, ~384 cy/CU-job) and the L2 path (B, ~550 cy) under MFMA (621 cy).
//   4 waves/block (1m x 4n), per-wave 64x64 out; 512 blocks = 2/CU. ----
__global__ void __launch_bounds__(256, 2)
k_gemm(const unsigned short* __restrict__ HVb, const unsigned short* __restrict__ Wb,
       float* __restrict__ m1, float* __restrict__ m2) {
  __shared__ __align__(16) unsigned short As[4 * AM * 64];   // 32 KB, 4 chunks (64-K)
  const int tid = threadIdx.x;
  const int lane = tid & 63, wn4 = tid >> 6;     // 4 waves = 4 n-quarters
  const int L = blockIdx.x;                      // [0,512)
  const int xcd = L & 7, rr = L >> 3;            // rr in [0,64)
  const int strip = xcd * 2 + (rr >> 5);         // [0,16): strip pinned to one XCD
  const int bm = (rr & 31) * AM;
  const int q = lane >> 4, ln = lane & 15;

  const int ntmine = NTILES / NSTRIP + (strip < (NTILES % NSTRIP) ? 1 : 0); // 12 or 13

  // ---- stage A strip once: 4 chunks x 512 granules ----
#pragma unroll
  for (int c = 0; c < 4; ++c)
#pragma unroll
    for (int i = 0; i < 2; ++i) {
      int G = i * 256 + tid;                     // [0,512)
      int row = G >> 3, slot = G & 7;
      int kg = slot ^ (row & 7);
      async16(HVb + (bm + row) * NDIM + c * 64 + kg * 8,
              (char*)As + c * 8192 + G * 16);
    }

  // A frag read byte-offsets (swizzled); chunk-half parity toggles bit 6
  int aoffq[4];
#pragma unroll
  for (int mi = 0; mi < 4; ++mi) {
    int row = mi * 16 + ln;
    aoffq[mi] = row * 128 + ((q ^ (row & 7)) << 4);
  }

  __syncthreads();                               // A staged (drains the 8 DMA ops)

  // B fragment pointer for this wave's 4 n-subtiles (shorts)
  const unsigned short* bp =
      Wb + (size_t)strip * 65536 + (size_t)wn4 * 16384 + (size_t)lane * 8;

  short8 fa0[4], fa1[4], fb0[4], fb1[4];
  float ps1[4][4] = {}, ps2[4][4] = {};

#define RDA(CN, FA)                                                           \
  {                                                                           \
    const char* Ac = (const char*)As + ((((CN)) & 7) >> 1) * 8192;            \
    const int axor = (((CN)) & 1) << 6;                                       \
    _Pragma("unroll") for (int mi = 0; mi < 4; ++mi)                          \
        FA[mi] = *(const short8*)(Ac + (aoffq[mi] ^ axor));                   \
  }
#define RDB(BP, CN, FB)                                                       \
  _Pragma("unroll") for (int ni = 0; ni < 4; ++ni)                            \
      FB[ni] = *(const short8*)((BP) + (CN) * 512 + ni * 4096);
#define MM(FA, FB)                                                            \
  {                                                                           \
    __builtin_amdgcn_s_setprio(1);                                            \
    _Pragma("unroll") for (int mi = 0; mi < 4; ++mi)                          \
        _Pragma("unroll") for (int ni = 0; ni < 4; ++ni)                      \
            acc[mi][ni] = __builtin_amdgcn_mfma_f32_16x16x32_bf16(            \
                FA[mi], FB[ni], acc[mi][ni], 0, 0, 0);                        \
    __builtin_amdgcn_s_setprio(0);                                            \
  }

  RDA(0, fa0); RDB(bp, 0, fb0);                  // prologue frags
  for (int ti = 0; ti < ntmine; ++ti) {
    const unsigned short* bpn =
        (ti + 1 < ntmine) ? bp + (size_t)NSTRIP * 65536 : bp;   // clamp = dummy
    f32x4 acc[4][4] = {};
    RDA(1, fa1); RDB(bp, 1, fb1);  MM(fa0, fb0);
    RDA(2, fa0); RDB(bp, 2, fb0);  MM(fa1, fb1);
    RDA(3, fa1); RDB(bp, 3, fb1);  MM(fa0, fb0);
    RDA(4, fa0); RDB(bp, 4, fb0);  MM(fa1, fb1);
    RDA(5, fa1); RDB(bp, 5, fb1);  MM(fa0, fb0);
    RDA(6, fa0); RDB(bp, 6, fb0);  MM(fa1, fb1);
    RDA(7, fa1); RDB(bp, 7, fb1);  MM(fa0, fb0);
    RDA(0, fa0); RDB(bpn, 0, fb0); MM(fa1, fb1); // preload next tile's phase 0
    bp = bpn;
    // consume acc into register power sums (pad cols contribute e^-30 ~ 0);
    // overlaps the next tile's phase-0 load latency
#pragma unroll
    for (int mi = 0; mi < 4; ++mi)
#pragma unroll
      for (int reg = 0; reg < 4; ++reg) {
        float s1 = 0.f, s2 = 0.f;
#pragma unroll
        for (int ni = 0; ni < 4; ++ni) {
          float e1 = __expf(acc[mi][ni][reg] - SHIFT);
          s1 += e1; s2 += e1 * e1;
        }
        ps1[mi][reg] += s1;
        ps2[mi][reg] += s2;
      }
  }
#undef MM
#undef RDB
#undef RDA

  // one reduce + atomic round per block
#pragma unroll
  for (int mi = 0; mi < 4; ++mi)
#pragma unroll
    for (int reg = 0; reg < 4; ++reg) {
      float s1 = ps1[mi][reg], s2 = ps2[mi][reg];
      for (int m = 1; m < 16; m <<= 1) { s1 += __shfl_xor(s1, m); s2 += __shfl_xor(s2, m); }
      if (ln == 0) {
        int grow = bm + mi * 16 + q * 4 + reg;
        atomicAdd(&m1[grow], s1);
        atomicAdd(&m2[grow], s2);
      }
    }
}

// ---- K4: per-row loss assembly + scalar reduce ----
__global__ void k_finalize(const float* __restrict__ m1, const float* __restrict__ m2,
                           const float* __restrict__ zlab, float* __restrict__ out) {
  __shared__ float red[16];
  int tid = threadIdx.x;  // 1024 threads
  float local = 0.f;
  for (int r = tid; r < MROWS; r += 1024) {
    float M1 = m1[r];
    float lse = SHIFT + logf(M1);
    float zl = zlab[r];
    float lp = fmaxf(zl - lse, -100.f);                 // log p_label
    float pl = __expf(zl - lse);
    float l1m = fmaxf(log1pf(-pl), -100.f);             // log(1-p_label)
    float iM1 = 1.f / M1;
    float r2 = m2[r] * iM1 * iM1;
    // sum_e log1p(-p_e) = -(1 + sum p^2/2 + O(p^3)); sum p == 1 exactly
    float series = -(1.f + 0.5f * r2);
    local += lp - l1m + series;
  }
  for (int m = 1; m < 64; m <<= 1) local += __shfl_xor(local, m);
  if ((tid & 63) == 0) red[tid >> 6] = local;
  __syncthreads();
  if (tid == 0) {
    float s = 0.f;
    for (int i = 0; i < 16; ++i) s += red[i];
    out[0] = -s / ((float)BATCH * (float)N_ENT);
  }
}

extern "C" void kernel_launch(void* const* d_in, const int* in_sizes, int n_in,
                              void* d_out, int out_size, void* d_ws, size_t ws_size,
                              hipStream_t stream) {
  const int* facts = (const int*)d_in[0];
  const int* arch = (const int*)d_in[1];
  const float* ent_w = (const float*)d_in[2];
  const float* rel_w = (const float*)d_in[3];
  const float* bne_g = (const float*)d_in[4];
  const float* bne_b = (const float*)d_in[5];
  const float* bnr_g = (const float*)d_in[6];
  const float* bnr_b = (const float*)d_in[7];
  char* ws = (char*)d_ws;
  // layout: [stats 6144][m1 8192][m2 8192][zlab 8192][HVb 1MB][Wb 25.7MB]
  float* stats = (float*)ws;
  float* m1 = (float*)(ws + 6144);
  float* m2 = (float*)(ws + 14336);
  float* zlab = (float*)(ws + 22528);
  unsigned short* HVb = (unsigned short*)(ws + 30720);
  unsigned short* Wb = (unsigned short*)(ws + 30720 + 1048576);

  hipMemsetAsync(ws, 0, 22528, stream);  // stats + m1 + m2
  k_convert<<<dim3(N_ENT_P / 16), dim3(256), 0, stream>>>(ent_w, Wb);
  k_stats<<<dim3(64, 3), dim3(256), 0, stream>>>(facts, ent_w, rel_w, stats);
  k_vectors<<<dim3(BATCH), dim3(256), 0, stream>>>(facts, arch, ent_w, rel_w,
                                                   bne_g, bne_b, bnr_g, bnr_b,
                                                   stats, HVb, zlab);
  k_gemm<<<dim3(512), dim3(256), 0, stream>>>(HVb, Wb, m1, m2);
  k_finalize<<<dim3(1), dim3(1024), 0, stream>>>(m1, m2, zlab, (float*)d_out);
}